// Round 7
// baseline (182.754 us; speedup 1.0000x reference)
//
#include <hip/hip_runtime.h>
#include <hip/hip_fp16.h>

// Problem constants (match reference)
#define BB      2048
#define CC      1024
#define FF      128
#define NBLK    256      // == CU count: 1 block/CU (capacity allows 2/CU)
#define RPB     8        // rows per block (NBLK*RPB == BB)
#define TPB     512      // 8 waves/block
#define NITER   10
#define SUBR    8        // colsum spread: [k][c] layout, wave-coalesced adds
#define SCALING_F (2048.0f / 100000.0f)

// Barrier tree geometry
#define NLEAF   8        // leaf counters per barrier slot
#define LPB     32       // blocks per leaf (NBLK/NLEAF)
#define NSLOT   (NITER + 1)   // 10 iteration barriers + 1 phase-0 barrier
#define CPAD    16       // pad counters to own 64B line

// Static device storage: no hipMalloc, graph-capture safe. All cross-block
// data goes through agent-scope atomics or sc0/sc1 (L2-bypassing) accesses,
// serviced at the IF coherence point -> no cache fences needed anywhere.
// All sync counters are MONOTONIC (never reset): windows derived from a
// per-launch epoch make them race-free across graph replays.
__device__ unsigned g_epoch;                    // launches so far * NBLK
__device__ unsigned g_leaf[NSLOT * NLEAF * CPAD];
__device__ unsigned g_root[NSLOT * CPAD];
__device__ unsigned g_rel [NSLOT * CPAD];       // release flag, own line
__device__ float g_meanPart[NBLK];              // per-block D partial sums
__device__ float g_colsum[NITER * SUBR * CC];   // [t][k][c] — c contiguous!

__device__ __forceinline__ float atomLoadF(const float* p) {
    return __hip_atomic_load(p, __ATOMIC_RELAXED, __HIP_MEMORY_SCOPE_AGENT);
}
__device__ __forceinline__ void atomStoreF(float* p, float v) {
    __hip_atomic_store(p, v, __ATOMIC_RELAXED, __HIP_MEMORY_SCOPE_AGENT);
}
__device__ __forceinline__ unsigned atomAddU(unsigned* p) {
    return __hip_atomic_fetch_add(p, 1u, __ATOMIC_RELAXED,
                                  __HIP_MEMORY_SCOPE_AGENT);
}

// Uncached (L2-bypassing) 4x16B pipelined loads of stable post-barrier data.
// sc0 sc1 = gfx94x/gfx950 system-coherent load encoding (reads at LLC, where
// the drained atomicAdds live; per-XCD L2s may hold stale lines from earlier
// launches, so plain cached loads would be WRONG here).
// Single asm block: 4 loads issued back-to-back, one vmcnt(0); consumers
// data-depend on the early-clobbered outputs -> no hoisting hazard.
__device__ __forceinline__ void llc_load4x4(const float* p0, const float* p1,
                                            const float* p2, const float* p3,
                                            float4& a0, float4& a1,
                                            float4& a2, float4& a3) {
    asm volatile(
        "global_load_dwordx4 %0, %4, off sc0 sc1\n\t"
        "global_load_dwordx4 %1, %5, off sc0 sc1\n\t"
        "global_load_dwordx4 %2, %6, off sc0 sc1\n\t"
        "global_load_dwordx4 %3, %7, off sc0 sc1\n\t"
        "s_waitcnt vmcnt(0)"
        : "=&v"(a0), "=&v"(a1), "=&v"(a2), "=&v"(a3)
        : "v"(p0), "v"(p1), "v"(p2), "v"(p3)
        : "memory");
}

// Tree grid barrier (proven round-6). Arrival RMWs spread over 8 leaf lines
// + 1 root line; release is a plain store to a DEDICATED line that pollers
// read -> poll traffic never interferes with arrival RMWs.
__device__ __forceinline__ void tree_barrier(int slot, unsigned e,
                                             int bid, int tid) {
    __syncthreads();
    if (tid == 0) {
        const int leaf = bid >> 5;     // 32 consecutive bids per leaf
        unsigned rl = atomAddU(&g_leaf[(slot * NLEAF + leaf) * CPAD]);
        if (rl == e * LPB + (LPB - 1)) {           // last of this leaf
            unsigned rr = atomAddU(&g_root[slot * CPAD]);
            if (rr == e * NLEAF + (NLEAF - 1))     // last leaf overall
                __hip_atomic_store(&g_rel[slot * CPAD], e + 1u,
                                   __ATOMIC_RELAXED, __HIP_MEMORY_SCOPE_AGENT);
        }
        while ((int)(__hip_atomic_load(&g_rel[slot * CPAD], __ATOMIC_RELAXED,
                                       __HIP_MEMORY_SCOPE_AGENT) - (e + 1u)) < 0)
            ;
    }
    __syncthreads();
}

__global__ void __launch_bounds__(TPB)
fused_sinkhorn(const int* __restrict__ users, const int* __restrict__ items,
               const float* __restrict__ D, const float* __restrict__ caps,
               const float* __restrict__ iemb, const float* __restrict__ uemb,
               float* __restrict__ out) {
    const int bid = blockIdx.x, tid = threadIdx.x;
    const int r0 = bid * RPB;

    // LDS: 4 + 16 + 32 KB = ~52.5 KB/block -> 1 block/CU
    __shared__ union { float ue[RPB][FF]; float v[CC]; } uv;  // GEMM then v
    __shared__ __half dott[RPB][CC];   // 16 KB (phase0 -> phase1 only)
    __shared__ float  Kt[RPB][CC];     // 32 KB: K, phase1 to the end
    __shared__ float  ush[RPB];
    __shared__ float  red[TPB / 64];
    __shared__ float  s2sh;
    __shared__ unsigned s_epoch;

    // ---------------- phase 0 (everything independent of grid) --------------
    // launch epoch: one RMW per block; all blocks of a launch see the same
    // e = ret/NBLK because launches are stream-serialized.
    if (tid == 0) s_epoch = atomAddU(&g_epoch) >> 8;   // /NBLK

    // v-fill ownership: thread pair (cg, kh): columns 4cg..4cg+3, k 4kh..4kh+3
    const int cg = tid >> 1;       // 0..255
    const int kh = tid & 1;        // 0..1
    float4 capv = ((const float4*)caps)[cg];
    capv.x *= SCALING_F; capv.y *= SCALING_F;
    capv.z *= SCALING_F; capv.w *= SCALING_F;

    // Register prefetches: D rows + items rows for THIS block so phase 1
    // never waits on HBM after the barrier.
    const float4* Dg  = (const float4*)(D + ((size_t)r0 << 10));
    const int4*   it4 = (const int4*)(items + ((size_t)r0 << 10));
    float4 d_reg[4];
    int4   it_reg[4];
    #pragma unroll
    for (int k = 0; k < 4; ++k) d_reg[k]  = Dg[tid + k * TPB];
    #pragma unroll
    for (int k = 0; k < 4; ++k) it_reg[k] = it4[tid + k * TPB];

    // zero colsum accumulators (atomic stores -> visible at IF)
    for (int i = bid * TPB + tid; i < NITER * SUBR * CC; i += NBLK * TPB)
        atomStoreF(&g_colsum[i], 0.0f);

    // stage 8 user embeddings (8 rows x 32 float4)
    if (tid < 256) {
        int r = tid >> 5, f4 = tid & 31;
        int u = users[r0 + r];
        ((float4*)uv.ue[r])[f4] = ((const float4*)(uemb + (size_t)u * FF))[f4];
    }

    // block partial sum of D (from the register prefetch)
    float p = 0.0f;
    #pragma unroll
    for (int k = 0; k < 4; ++k) {
        float4 d = d_reg[k];
        p += d.x + d.y + d.z + d.w;
    }
    #pragma unroll
    for (int off = 32; off > 0; off >>= 1) p += __shfl_down(p, off, 64);
    if ((tid & 63) == 0) red[tid >> 6] = p;
    __syncthreads();             // publishes uv.ue, red, s_epoch
    const unsigned e = s_epoch;
    if (tid == 0) {
        float s = 0.0f;
        #pragma unroll
        for (int k = 0; k < TPB / 64; ++k) s += red[k];
        atomStoreF(&g_meanPart[bid], s);
    }

    // dot GEMM: dott[r][j] = ue[r] . iemb[j]; both j-columns fused so each
    // LDS broadcast read of b feeds 2 outputs.
    {
        const float4* us  = (const float4*)uv.ue;
        const float4* ip0 = (const float4*)(iemb + (size_t)tid * FF);
        const float4* ip1 = (const float4*)(iemb + (size_t)(tid + 512) * FF);
        float acc0[RPB] = {}, acc1[RPB] = {};
        for (int f4 = 0; f4 < FF / 4; ++f4) {
            float4 a0 = ip0[f4], a1 = ip1[f4];
            #pragma unroll
            for (int r = 0; r < RPB; ++r) {
                float4 b = us[r * (FF / 4) + f4];   // broadcast LDS read
                acc0[r] += a0.x * b.x + a0.y * b.y + a0.z * b.z + a0.w * b.w;
                acc1[r] += a1.x * b.x + a1.y * b.y + a1.z * b.z + a1.w * b.w;
            }
        }
        #pragma unroll
        for (int r = 0; r < RPB; ++r) {
            dott[r][tid]       = __float2half(acc0[r]);
            dott[r][tid + 512] = __float2half(acc1[r]);
        }
    }

    tree_barrier(NITER, e, bid, tid);  // colsum zeros + meanPart complete

    // ---------------- phase 1: s2, K built in LDS (regs -> no HBM wait) -----
    if (tid < 64) {
        float s = 0.0f;
        #pragma unroll
        for (int k = 0; k < NBLK / 64; ++k)
            s += atomLoadF(&g_meanPart[tid + 64 * k]);
        #pragma unroll
        for (int off = 32; off > 0; off >>= 1) s += __shfl_down(s, off, 64);
        if (tid == 0) s2sh = 5.0f * (float)(BB * CC) / s;
    }
    __syncthreads();
    const float s2 = s2sh;
    float4* KtL = (float4*)Kt;
    #pragma unroll
    for (int k = 0; k < 4; ++k) {
        int    i  = tid + k * TPB;
        int4   iv = it_reg[k];
        float4 d  = d_reg[k];
        int    r  = i >> 8;                 // (i*4)>>10
        float4 kv;
        kv.x = __expf(5.0f * __half2float(dott[r][iv.x]) - s2 * d.x);
        kv.y = __expf(5.0f * __half2float(dott[r][iv.y]) - s2 * d.y);
        kv.z = __expf(5.0f * __half2float(dott[r][iv.z]) - s2 * d.z);
        kv.w = __expf(5.0f * __half2float(dott[r][iv.w]) - s2 * d.w);
        KtL[i] = kv;                        // K lives in LDS until the end
    }

    // ---------------- Sinkhorn iterations -----------------------------------
    for (int t = 0; t < NITER; ++t) {
        // vsh fill: v_0 = 1; else v[c] = b_c / colsum[t-1][c].
        // 4x dwordx4 uncached loads per thread (pipelined), pair-combined
        // with shfl_xor; even thread of each pair writes 4 columns of v.
        if (t == 0) {
            uv.v[tid]       = 1.0f;
            uv.v[tid + 512] = 1.0f;
        } else {
            const float* base = g_colsum + (size_t)(t - 1) * SUBR * CC
                              + (size_t)(kh * 4) * CC + (cg << 2);
            float4 a0, a1, a2, a3;
            llc_load4x4(base, base + CC, base + 2 * CC, base + 3 * CC,
                        a0, a1, a2, a3);
            float4 s;
            s.x = (a0.x + a1.x) + (a2.x + a3.x);
            s.y = (a0.y + a1.y) + (a2.y + a3.y);
            s.z = (a0.z + a1.z) + (a2.z + a3.z);
            s.w = (a0.w + a1.w) + (a2.w + a3.w);
            s.x += __shfl_xor(s.x, 1, 64);
            s.y += __shfl_xor(s.y, 1, 64);
            s.z += __shfl_xor(s.z, 1, 64);
            s.w += __shfl_xor(s.w, 1, 64);
            if (kh == 0) {
                float4 v4;
                v4.x = capv.x / s.x;  v4.y = capv.y / s.y;
                v4.z = capv.z / s.z;  v4.w = capv.w / s.w;
                ((float4*)uv.v)[cg] = v4;
            }
        }
        __syncthreads();

        // u_r = 1/(K v)_r : one wave per row
        {
            int r = tid >> 6, l = tid & 63;
            const float4* kr = (const float4*)Kt[r];
            const float4* v4 = (const float4*)uv.v;
            float pp = 0.0f;
            #pragma unroll
            for (int i2 = 0; i2 < 4; ++i2) {
                float4 k = kr[l + i2 * 64], v = v4[l + i2 * 64];
                pp += k.x * v.x + k.y * v.y + k.z * v.z + k.w * v.w;
            }
            #pragma unroll
            for (int off = 32; off > 0; off >>= 1) pp += __shfl_down(pp, off, 64);
            if (l == 0) ush[r] = 1.0f / pp;
        }
        __syncthreads();

        // colsum[t] += K^T u : 2 wave-coalesced atomicAdds per thread
        {
            float* cb = g_colsum + ((size_t)t * SUBR + (bid & (SUBR - 1))) * CC;
            float sA = 0.0f, sB = 0.0f;
            #pragma unroll
            for (int r = 0; r < RPB; ++r) {
                sA += Kt[r][tid]       * ush[r];
                sB += Kt[r][tid + 512] * ush[r];
            }
            atomicAdd(&cb[tid],       sA);
            atomicAdd(&cb[tid + 512], sB);
        }

        tree_barrier(t, e, bid, tid);  // all colsum[t] adds performed at LLC
    }

    // ---------------- final: v10 from colsum[9], P = K * u10 (x) v10 --------
    // ush still holds u10 from iteration t=9
    {
        const float* base = g_colsum + (size_t)(NITER - 1) * SUBR * CC
                          + (size_t)(kh * 4) * CC + (cg << 2);
        float4 a0, a1, a2, a3;
        llc_load4x4(base, base + CC, base + 2 * CC, base + 3 * CC,
                    a0, a1, a2, a3);
        float4 s;
        s.x = (a0.x + a1.x) + (a2.x + a3.x);
        s.y = (a0.y + a1.y) + (a2.y + a3.y);
        s.z = (a0.z + a1.z) + (a2.z + a3.z);
        s.w = (a0.w + a1.w) + (a2.w + a3.w);
        s.x += __shfl_xor(s.x, 1, 64);
        s.y += __shfl_xor(s.y, 1, 64);
        s.z += __shfl_xor(s.z, 1, 64);
        s.w += __shfl_xor(s.w, 1, 64);
        if (kh == 0) {
            float4 v4;
            v4.x = capv.x / s.x;  v4.y = capv.y / s.y;
            v4.z = capv.z / s.z;  v4.w = capv.w / s.w;
            ((float4*)uv.v)[cg] = v4;
        }
    }
    __syncthreads();

    float4* o4 = (float4*)(out + ((size_t)r0 << 10));
    #pragma unroll
    for (int k = 0; k < 4; ++k) {
        int    i  = tid + k * TPB;
        int    r  = i >> 8;
        float4 kk = KtL[i];
        float  ur = ush[r];
        float4 v  = *(const float4*)&uv.v[(i * 4) & (CC - 1)];
        float4 pv;
        pv.x = kk.x * ur * v.x;  pv.y = kk.y * ur * v.y;
        pv.z = kk.z * ur * v.z;  pv.w = kk.w * ur * v.w;
        o4[i] = pv;
    }
}

extern "C" void kernel_launch(void* const* d_in, const int* in_sizes, int n_in,
                              void* d_out, int out_size, void* d_ws, size_t ws_size,
                              hipStream_t stream) {
    const int*   users = (const int*)d_in[0];
    const int*   items = (const int*)d_in[1];
    const float* D     = (const float*)d_in[2];
    const float* caps  = (const float*)d_in[3];
    const float* iemb  = (const float*)d_in[4];
    const float* uemb  = (const float*)d_in[5];
    float* out = (float*)d_out;

    // Plain launch (graph-capture friendly). Co-residency of all 256 blocks
    // is guaranteed by capacity arithmetic (52.5 KB LDS, 8 waves -> 2
    // blocks/CU possible), which the monotonic tree barrier requires.
    hipLaunchKernelGGL(fused_sinkhorn, dim3(NBLK), dim3(TPB), 0, stream,
                       users, items, D, caps, iemb, uemb, out);
}